// Round 6
// baseline (939.497 us; speedup 1.0000x reference)
//
#include <hip/hip_runtime.h>

typedef unsigned char u8;
typedef unsigned short u16;

#define TT 1024
#define BB 512
#define LL 50
#define STOPI 48
#define STARTI 49
#define NEGV -10000.0f

// Swizzled in-LDS backpointer array lptr[50][1024] (bytes).
#define PDW(TO, T4) (((TO) << 8) + ((T4) ^ ((TO) & 31)))
#define PBYTE(S, T) ((((S) << 10) + (((((T) >> 2) ^ ((S) & 31))) << 2)) + ((T) & 3))

// value-only max over S[0..49] via max3 tree (~26 instrs, depth 4)
#define MAX50(S, M)                                                            \
    {                                                                          \
        float r0_[17];                                                         \
        _Pragma("unroll")                                                      \
        for (int k_ = 0; k_ < 16; ++k_)                                        \
            r0_[k_] = fmaxf(fmaxf((S)[3*k_], (S)[3*k_+1]), (S)[3*k_+2]);       \
        r0_[16] = fmaxf((S)[48], (S)[49]);                                     \
        float r1_[6];                                                          \
        _Pragma("unroll")                                                      \
        for (int k_ = 0; k_ < 5; ++k_)                                         \
            r1_[k_] = fmaxf(fmaxf(r0_[3*k_], r0_[3*k_+1]), r0_[3*k_+2]);       \
        r1_[5] = fmaxf(r0_[15], r0_[16]);                                      \
        (M) = fmaxf(fmaxf(fmaxf(r1_[0], r1_[1]), r1_[2]),                      \
                    fmaxf(fmaxf(r1_[3], r1_[4]), r1_[5]));                     \
    }

// consumer fast argmax: m is the producer-published max (bitwise one of a_j).
// Stream the row (13 uniform b128 broadcasts), a_j = row[j]+trr[j] (bitwise
// identical to producer), idx = min_j { j : a_j == m } via 4 parallel
// independent min chains -- no vcc serialization, no a[50] live range.
// min-of-equals == FIRST index attaining the max == jnp.argmax tie rule.
#define FASTIDX(T, IOUT)                                                       \
    {                                                                          \
        const float  m_    = mring[(T) & 15][lane];                            \
        const float* rowp_ = &ring[(T) & 15][0];                               \
        int ia_ = 63, ib_ = 63, ic_ = 63, id_ = 63;                            \
        _Pragma("unroll")                                                      \
        for (int k_ = 0; k_ < 13; ++k_) {                                      \
            const float4 q_ = *(const float4*)(rowp_ + 4 * k_);                \
            const int j_ = 4 * k_;                                             \
            { float a_ = q_.x + trr[j_+0]; int c_ = (a_==m_) ? (j_+0) : 63;    \
              ia_ = c_ < ia_ ? c_ : ia_; }                                     \
            { float a_ = q_.y + trr[j_+1]; int c_ = (a_==m_) ? (j_+1) : 63;    \
              ib_ = c_ < ib_ ? c_ : ib_; }                                     \
            if (j_+2 < LL) { float a_ = q_.z + trr[j_+2];                      \
              int c_ = (a_==m_) ? (j_+2) : 63; ic_ = c_ < ic_ ? c_ : ic_; }    \
            if (j_+3 < LL) { float a_ = q_.w + trr[j_+3];                      \
              int c_ = (a_==m_) ? (j_+3) : 63; id_ = c_ < id_ ? c_ : id_; }    \
        }                                                                      \
        const int m0_ = ia_ < ib_ ? ia_ : ib_;                                 \
        const int m1_ = ic_ < id_ ? ic_ : id_;                                 \
        (IOUT) = m0_ < m1_ ? m0_ : m1_;                                        \
    }

// frozen-row argmax (once per wave): two-pass tree + eq-scan, m computed here
#define TREEIDX(T, IOUT)                                                       \
    {                                                                          \
        const float* rowp_ = &ring[(T) & 15][0];                               \
        float a_[LL];                                                          \
        _Pragma("unroll")                                                      \
        for (int k_ = 0; k_ < 13; ++k_) {                                      \
            const float4 q_ = *(const float4*)(rowp_ + 4 * k_);                \
            const int j_ = 4 * k_;                                             \
            a_[j_+0] = q_.x + trr[j_+0];                                       \
            a_[j_+1] = q_.y + trr[j_+1];                                       \
            if (j_+2 < LL) a_[j_+2] = q_.z + trr[j_+2];                        \
            if (j_+3 < LL) a_[j_+3] = q_.w + trr[j_+3];                        \
        }                                                                      \
        float m_; MAX50(a_, m_)                                                \
        int ii_ = 0;                                                           \
        _Pragma("unroll")                                                      \
        for (int j_ = LL - 1; j_ >= 0; --j_)                                   \
            if (a_[j_] == m_) ii_ = j_;                                        \
        (IOUT) = ii_;                                                          \
    }

// consumer: two adjacent rows -> one b16 store into swizzled lptr
#define PAIR_FAST(B0)                                                          \
    {                                                                          \
        int i0_, i1_;                                                          \
        FASTIDX((B0),     i0_)                                                 \
        FASTIDX((B0) + 1, i1_)                                                 \
        if (lane < LL)                                                         \
            *(u16*)(lptr + PBYTE(row, (B0))) = (u16)(i0_ | (i1_ << 8));        \
    }

#define PAIR_MIXED(B0)                                                         \
    {                                                                          \
        int i0_, i1_;                                                          \
        { const int t_ = (B0);                                                 \
          if (t_ < len) { FASTIDX(t_, i0_) }                                   \
          else { if (!have) { TREEIDX(len, cidx) have = true; } i0_ = cidx; } }\
        { const int t_ = (B0) + 1;                                             \
          if (t_ < len) { FASTIDX(t_, i1_) }                                   \
          else { if (!have) { TREEIDX(len, cidx) have = true; } i1_ = cidx; } }\
        if (lane < LL)                                                         \
            *(u16*)(lptr + PBYTE(row, (B0))) = (u16)(i0_ | (i1_ << 8));        \
    }

// ---------------------------------------------------------------------------
// One kernel, one batch per block, 5 waves:
//   wave 0 (producer, prio 1): max-only serial chain; publishes the vit row
//     AND its max m to LDS rings each step.
//   waves 1..4 (consumers): one iteration behind; 2 rows each per iteration;
//     cheap m-guided first-index argmax; b16 stores into swizzled LDS lptr.
//   then all 5 waves: chunked pointer-jumping backtrack from LDS.
// In-loop consumer rows are provably < len, so the hot loop has no frozen
// branch. One bare s_barrier (+lgkmcnt(0)) per 8 steps; vmcnt never drained.
// ---------------------------------------------------------------------------
__global__ __launch_bounds__(320, 2) void viterbi_all(
    const float* __restrict__ feats, const int* __restrict__ lens,
    const float* __restrict__ trans, float* __restrict__ out)
{
    const int b    = blockIdx.x;
    const int tid  = threadIdx.x;
    const int lane = tid & 63;
    const int w    = __builtin_amdgcn_readfirstlane(tid >> 6);   // 0..4
    const int row  = (lane < LL) ? lane : (LL - 1);              // 'to' label

    __shared__ float ring[16][64];     // vit rows, slot = t & 15
    __shared__ float mring[16][64];    // per-step max rows, slot = t & 15
    __shared__ u8    lptr[TT * LL];    // 51200 B backpointers, swizzled
    __shared__ u8    maps[32 * LL];
    __shared__ int   entries[33];
    __shared__ int   fidx;

    float trr[LL];
#pragma unroll
    for (int j = 0; j < LL; ++j) trr[j] = trans[row * LL + j];
#pragma unroll
    for (int j = 0; j < LL; ++j) asm("" : "+v"(trr[j]));   // keep resident

    const int len  = lens[b];
    const int nit0 = (len >> 3) + 1;
    const int nit  = nit0 > 128 ? 128 : nit0;

    if (w == 0) {
        // ---------------- producer: register-resident max chain ----------
        __builtin_amdgcn_s_setprio(1);
        const float tr_stop = trans[STOPI * LL + row];
        float vit = (lane == STARTI) ? 0.0f : NEGV;
        const float* fb = feats + (size_t)b * (TT * LL);

        float f[8];
#pragma unroll
        for (int i = 0; i < 8; ++i) f[i] = fb[i * LL + row];

        for (int it = 0; it < nit; ++it) {
#pragma unroll
            for (int i = 0; i < 8; ++i) {
                const int t = (it << 3) + i;
                if (t <= len) {                     // publish pre-update row
                    if (lane < LL) ring[t & 15][lane] = vit;
                }
                if (t < len) {                      // wave-uniform
                    float a[LL];
#pragma unroll
                    for (int j = 0; j < LL; ++j)
                        a[j] = __int_as_float(__builtin_amdgcn_readlane(
                                   __float_as_int(vit), j)) + trr[j];
                    float m; MAX50(a, m)
                    if (lane < LL) mring[t & 15][lane] = m;   // publish max
                    float nv = m + f[i];
                    if (t == len - 1) nv += tr_stop;
                    vit = nv;
                    int tp = t + 8; if (tp > TT - 1) tp = TT - 1;
                    f[i] = fb[(size_t)tp * LL + row];
                }
            }
            asm volatile("s_waitcnt lgkmcnt(0)" ::: "memory");
            __builtin_amdgcn_s_barrier();
            asm volatile("" ::: "memory");
        }
        __builtin_amdgcn_s_setprio(0);

        // final score / first-index argmax
        float m = -3.4e38f; int mi = 0;
#pragma unroll
        for (int j = 0; j < LL; ++j) {
            float sv = __int_as_float(__builtin_amdgcn_readlane(__float_as_int(vit), j));
            if (sv > m) { m = sv; mi = j; }
        }
        if (lane == 0) { out[b] = m; fidx = mi; }
    } else {
        // ---------------- consumers: 2 rows each per iteration ------------
        int  cidx = 0;
        bool have = false;
        const int k0 = (w - 1) << 1;     // row offset within the 8-step group

        for (int it = 0; it < nit; ++it) {
            if (it > 0) {
                const int base = ((it - 1) << 3) + k0;   // rows proven < len
                PAIR_FAST(base)
            }
            asm volatile("s_waitcnt lgkmcnt(0)" ::: "memory");
            __builtin_amdgcn_s_barrier();
            asm volatile("" ::: "memory");
        }

        // tail: rows of the last iteration (ring static now); may straddle len
        {
            const int base = ((nit - 1) << 3) + k0;
            PAIR_MIXED(base)
        }

        // frozen pattern fill for t >= nit*8 (all >= len by construction)
        const int t0f = nit << 3;
        if (t0f < TT) {
            if (!have) { TREEIDX(len, cidx) have = true; }
            if (lane < LL) {
                const unsigned pat = (unsigned)cidx * 0x01010101u;
                for (int t4 = (t0f >> 2) + (w - 1); t4 < 256; t4 += 4)
                    ((unsigned*)lptr)[PDW(row, t4)] = pat;
            }
        }
    }

    __syncthreads();   // all backpointers in LDS; fidx visible

    // ---------------- backtrack (same block, from LDS) --------------------
    // phase 1: all 1600 (chunk, entry) walks; exactly 5 chains per thread
    {
        int st[5], ttt[5], ci[5];
#pragma unroll
        for (int k = 0; k < 5; ++k) {
            const int id = tid + 320 * k;        // 0..1599, all valid
            const int c = id / 50;
            const int l = id - c * 50;
            st[k] = l; ttt[k] = c * 32 + 31; ci[k] = id;
        }
        for (int j = 0; j < 32; ++j) {
#pragma unroll
            for (int k = 0; k < 5; ++k) {
                st[k] = lptr[PBYTE(st[k], ttt[k])];
                ttt[k] -= 1;
            }
        }
#pragma unroll
        for (int k = 0; k < 5; ++k) maps[ci[k]] = (u8)st[k];
    }
    __syncthreads();

    const int idx = fidx;

    // phase 2: compose chunk maps sequentially
    if (tid == 0) {
        int i = idx;
        for (int c = 31; c >= 0; --c) {
            entries[c + 1] = i;
            i = maps[c * 50 + i];
        }
        entries[0] = i;
    }
    __syncthreads();

    // phase 3: re-walk 32 chunks in parallel, writing the path
    float* po = out + BB + (size_t)b * TT;
    if (tid < 32) {
        const int c = tid;
        int s = entries[c + 1];
        for (int j = 0; j < 32; ++j) {
            int t = c * 32 + 31 - j;
            int ni = lptr[PBYTE(s, t)];
            if (t > 0) po[t - 1] = (float)ni;   // paths[t-1] = back_seq[t]
            s = ni;
        }
    }
    if (tid == 0) po[TT - 1] = (float)idx;      // paths[T-1] = argmax(vit)
}

extern "C" void kernel_launch(void* const* d_in, const int* in_sizes, int n_in,
                              void* d_out, int out_size, void* d_ws, size_t ws_size,
                              hipStream_t stream) {
    const float* feats = (const float*)d_in[0];
    const int*   lens  = (const int*)d_in[1];
    const float* trans = (const float*)d_in[2];

    viterbi_all<<<BB, 320, 0, stream>>>(feats, lens, trans, (float*)d_out);
}

// Round 7
// 626.538 us; speedup vs baseline: 1.4995x; 1.4995x over previous
//
#include <hip/hip_runtime.h>

typedef unsigned char u8;

#define TT 1024
#define BB 512
#define LL 50
#define STOPI 48
#define STARTI 49
#define NEGV -10000.0f

// ws layout:
//   [0, 2048)                  : int idx[512]
//   [4096, 4096+B*50*T)        : u8 ptr[B][50][T]   backpointers, [label][time]
//   [4096+B*50*T, +B*T*50*4)   : f32 vit[B][T][50]  per-step Viterbi rows
#define PTR_OFF   4096
#define PTR_BYTES ((size_t)BB * TT * LL)
#define VIT_OFF   (PTR_OFF + PTR_BYTES)

// value-only max over S[0..49] via max3 tree (~24 instrs, depth 4)
#define MAX50(S, M)                                                            \
    {                                                                          \
        float r0_[17];                                                         \
        _Pragma("unroll")                                                      \
        for (int k_ = 0; k_ < 16; ++k_)                                        \
            r0_[k_] = fmaxf(fmaxf((S)[3*k_], (S)[3*k_+1]), (S)[3*k_+2]);       \
        r0_[16] = fmaxf((S)[48], (S)[49]);                                     \
        float r1_[6];                                                          \
        _Pragma("unroll")                                                      \
        for (int k_ = 0; k_ < 5; ++k_)                                         \
            r1_[k_] = fmaxf(fmaxf(r0_[3*k_], r0_[3*k_+1]), r0_[3*k_+2]);       \
        r1_[5] = fmaxf(r0_[15], r0_[16]);                                      \
        (M) = fmaxf(fmaxf(fmaxf(r1_[0], r1_[1]), r1_[2]),                      \
                    fmaxf(fmaxf(r1_[3], r1_[4]), r1_[5]));                     \
    }

// ---------------------------------------------------------------------------
// K1: ISOLATED serial max-only chain. One wave per batch, one batch per block:
// 512 waves over 1024 SIMDs -> every wave has a private SIMD. No LDS, no
// barriers, no co-scheduled consumers. launch_bounds(64,1) lifts the VGPR cap
// to 512 so trr[50] + temps stay resident (rounds 2/3/5/6: heuristic chose
// 48-88 VGPRs and paid per-step reload/spill traffic on the chain).
// ---------------------------------------------------------------------------
__global__ __launch_bounds__(64, 1) void viterbi_max(
    const float* __restrict__ feats, const int* __restrict__ lens,
    const float* __restrict__ trans, float* __restrict__ out_scores,
    int* __restrict__ idx_ws, float* __restrict__ vit_ws)
{
    const int b    = blockIdx.x;
    const int lane = threadIdx.x;
    if (lane >= LL) return;                       // no barriers below; safe

    float trr[LL];
#pragma unroll
    for (int j = 0; j < LL; ++j) trr[j] = trans[lane * LL + j];
#pragma unroll
    for (int j = 0; j < LL; ++j) asm("" : "+v"(trr[j]));   // force resident
    const float tr_stop = trans[STOPI * LL + lane];
    const int len = lens[b];

    float vit = (lane == STARTI) ? 0.0f : NEGV;

    const float* fb  = feats  + (size_t)b * (TT * LL);
    float*       vst = vit_ws + (size_t)b * (TT * LL);

    float f[8];                      // feats prefetch ring, depth 8
#pragma unroll
    for (int i = 0; i < 8; ++i) f[i] = fb[i * LL + lane];

    // guard-free full iterations: t = it*8+i, with it*8+8 <= len => t < len
    const int nfull = len >> 3;
    for (int it = 0; it < nfull; ++it) {
#pragma unroll
        for (int i = 0; i < 8; ++i) {
            const int t = (it << 3) + i;
            vst[(size_t)t * LL + lane] = vit;     // row t = pre-update vit
            float x[LL];
#pragma unroll
            for (int j = 0; j < LL; ++j)
                x[j] = __int_as_float(__builtin_amdgcn_readlane(
                           __float_as_int(vit), j)) + trr[j];
            float m; MAX50(x, m)
            vit = m + f[i];
            int tp = t + 8; if (tp > TT - 1) tp = TT - 1;
            f[i] = fb[(size_t)tp * LL + lane];    // prefetch t+8
        }
    }

    // tail: <= 7 guarded steps (off the critical path for the longest block)
    for (int t = nfull << 3; t < len; ++t) {
        vst[(size_t)t * LL + lane] = vit;
        float x[LL];
#pragma unroll
        for (int j = 0; j < LL; ++j)
            x[j] = __int_as_float(__builtin_amdgcn_readlane(
                       __float_as_int(vit), j)) + trr[j];
        float m; MAX50(x, m)
        vit = m + fb[(size_t)t * LL + lane];
    }

    // stop transition: applied exactly once, at the t = len-1 update.
    // Equivalent to adding after the loop since it's the final update and
    // all later (frozen) state includes it.
    vit += tr_stop;

    // row 'len' (frozen vit, post-stop) for K2's r = min(t, len) lookup
    if (len < TT) vst[(size_t)len * LL + lane] = vit;

    // final score / first-index argmax (one-time)
    float m = -3.4e38f; int mi = 0;
#pragma unroll
    for (int j = 0; j < LL; ++j) {
        float s = __int_as_float(__builtin_amdgcn_readlane(__float_as_int(vit), j));
        if (s > m) { m = s; mi = j; }
    }
    if (lane == 0) { out_scores[b] = m; idx_ws[b] = mi; }
}

// ---------------------------------------------------------------------------
// K2: backpointer recompute, massively parallel (proven structure, round 2).
// One wave per (b, 8-step group); lane = 'to'. x_j = vit[r][j] + trr[j] is
// bitwise identical to K1's values; m via the same fmax tree (pure selection,
// m bitwise-equals some x_j); idx = min_j { j : x_j == m } via 4 independent
// chains == FIRST index attaining the max == jnp.argmax tie rule.
// Frozen rows (t >= len) dedupe via prev_r.
// ---------------------------------------------------------------------------
#define K2ROW(T, IDX)                                                          \
    {                                                                          \
        const int r_ = ((T) < len) ? (T) : len;                                \
        if (r_ != prev_r) {                                                    \
            prev_r = r_;                                                       \
            const float v_ = vbase[(size_t)r_ * LL + lane];                    \
            float x_[LL];                                                      \
            _Pragma("unroll")                                                  \
            for (int j_ = 0; j_ < LL; ++j_)                                    \
                x_[j_] = __int_as_float(__builtin_amdgcn_readlane(             \
                             __float_as_int(v_), j_)) + trr[j_];               \
            float m_; MAX50(x_, m_)                                            \
            int ia_ = 63, ib_ = 63, ic_ = 63, id_ = 63;                        \
            _Pragma("unroll")                                                  \
            for (int j_ = 0; j_ < 48; j_ += 4) {                               \
                { int c_ = (x_[j_+0]==m_) ? (j_+0) : 63; ia_ = c_<ia_?c_:ia_; }\
                { int c_ = (x_[j_+1]==m_) ? (j_+1) : 63; ib_ = c_<ib_?c_:ib_; }\
                { int c_ = (x_[j_+2]==m_) ? (j_+2) : 63; ic_ = c_<ic_?c_:ic_; }\
                { int c_ = (x_[j_+3]==m_) ? (j_+3) : 63; id_ = c_<id_?c_:id_; }\
            }                                                                  \
            { int c_ = (x_[48]==m_) ? 48 : 63; ia_ = c_<ia_?c_:ia_; }          \
            { int c_ = (x_[49]==m_) ? 49 : 63; ib_ = c_<ib_?c_:ib_; }          \
            const int m0_ = ia_ < ib_ ? ia_ : ib_;                             \
            const int m1_ = ic_ < id_ ? ic_ : id_;                             \
            cached = m0_ < m1_ ? m0_ : m1_;                                    \
        }                                                                      \
        (IDX) = cached;                                                        \
    }

__global__ __launch_bounds__(256, 2) void viterbi_ptr(
    const int* __restrict__ lens, const float* __restrict__ trans,
    const float* __restrict__ vit_ws, u8* __restrict__ ptr_ws)
{
    const int tid  = threadIdx.x;
    const int lane = tid & 63;
    if (lane >= LL) return;                        // no barriers below
    const int wid = (blockIdx.x << 2) | (tid >> 6);
    const int b   = wid >> 7;                      // 128 waves per batch
    const int t0  = (wid & 127) << 3;              // this wave's 8 steps

    float trr[LL];
#pragma unroll
    for (int j = 0; j < LL; ++j) trr[j] = trans[lane * LL + j];
#pragma unroll
    for (int j = 0; j < LL; ++j) asm("" : "+v"(trr[j]));
    const int len = lens[b];

    const float* vbase = vit_ws + (size_t)b * (TT * LL);
    u8* pt = ptr_ws + (size_t)b * (TT * LL) + (size_t)lane * TT;  // [to][t]

    int prev_r = -1, cached = 0;

    unsigned pk0 = 0;
#pragma unroll 1
    for (int g = 0; g < 4; ++g) {
        int idx; K2ROW(t0 + g, idx)
        pk0 |= (unsigned)idx << (8 * g);
    }
    unsigned pk1 = 0;
#pragma unroll 1
    for (int g = 4; g < 8; ++g) {
        int idx; K2ROW(t0 + g, idx)
        pk1 |= (unsigned)idx << (8 * (g - 4));
    }
    *(unsigned*)(pt + t0)     = pk0;
    *(unsigned*)(pt + t0 + 4) = pk1;
}

// ---------------------------------------------------------------------------
// K3: backtrack with chunked pointer-jumping; XOR-swizzled LDS (passed r2).
// byte (s,t) lives at (s<<10) + (t ^ ((s&31)<<2)).
// ---------------------------------------------------------------------------
#define LSW(S, T) (((S) << 10) + ((T) ^ (((S) & 31) << 2)))

__global__ __launch_bounds__(64) void viterbi_bwd(
    const int* __restrict__ idx_ws, const u8* __restrict__ ptr_ws,
    float* __restrict__ out_paths)
{
    const int b = blockIdx.x;
    const int lane = threadIdx.x;

    __shared__ u8 lptr[TT * LL];    // 51200 B, swizzled [label][t]
    __shared__ u8 maps[32 * LL];
    __shared__ int entries[33];

    {   // dword-level swizzled copy (XOR touches bits 0..4 of the dword index)
        const unsigned* src = (const unsigned*)(ptr_ws + (size_t)b * TT * LL);
        unsigned* dst = (unsigned*)lptr;
        for (int i = lane; i < (TT * LL) / 4; i += 64) {
            const int to = i >> 8;            // 256 dwords per label row
            const int t4 = i & 255;
            dst[(to << 8) + (t4 ^ (to & 31))] = src[i];
        }
    }
    __syncthreads();

    // phase 1: all 1600 (chunk, entry) walks; 25 chains per lane
    {
        int st[25], tt[25], cidx[25];
#pragma unroll
        for (int k = 0; k < 25; ++k) {
            int w = k * 64 + lane;
            int c = w / 50;
            int l = w - c * 50;
            st[k] = l;
            tt[k] = c * 32 + 31;
            cidx[k] = c * 50 + l;
        }
        for (int j = 0; j < 32; ++j) {
#pragma unroll
            for (int k = 0; k < 25; ++k) {
                st[k] = lptr[LSW(st[k], tt[k])];
                tt[k] -= 1;
            }
        }
#pragma unroll
        for (int k = 0; k < 25; ++k) maps[cidx[k]] = (u8)st[k];
    }
    __syncthreads();

    const int idx = idx_ws[b];

    // phase 2: compose chunk maps sequentially
    if (lane == 0) {
        int i = idx;
        for (int c = 31; c >= 0; --c) {
            entries[c + 1] = i;
            i = maps[c * 50 + i];
        }
        entries[0] = i;
    }
    __syncthreads();

    // phase 3: re-walk all 32 chunks in parallel, writing the path
    float* po = out_paths + (size_t)b * TT;
    if (lane < 32) {
        const int c = lane;
        int s = entries[c + 1];
        for (int j = 0; j < 32; ++j) {
            int t = c * 32 + 31 - j;
            int ni = lptr[LSW(s, t)];
            if (t > 0) po[t - 1] = (float)ni;
            s = ni;
        }
    }
    if (lane == 0) po[TT - 1] = (float)idx;
}

extern "C" void kernel_launch(void* const* d_in, const int* in_sizes, int n_in,
                              void* d_out, int out_size, void* d_ws, size_t ws_size,
                              hipStream_t stream) {
    const float* feats = (const float*)d_in[0];
    const int*   lens  = (const int*)d_in[1];
    const float* trans = (const float*)d_in[2];

    float* scores = (float*)d_out;          // [512]
    float* paths  = scores + BB;            // [512*1024]

    int*   idx_ws = (int*)d_ws;
    u8*    ptr_ws = (u8*)d_ws + PTR_OFF;
    float* vit_ws = (float*)((u8*)d_ws + VIT_OFF);

    viterbi_max<<<BB, 64, 0, stream>>>(feats, lens, trans, scores, idx_ws, vit_ws);
    viterbi_ptr<<<(BB * 128) / 4, 256, 0, stream>>>(lens, trans, vit_ws, ptr_ws);
    viterbi_bwd<<<BB, 64, 0, stream>>>(idx_ws, ptr_ws, paths);
}